// Round 7
// baseline (10238.374 us; speedup 1.0000x reference)
//
#include <hip/hip_runtime.h>
#include <hip/hip_bf16.h>
#include <math.h>

#define B_ 128
#define T_ 2048
#define D_ 256
#define U_ 512
#define G4_ 2048
#define KT_ 768            // 512 (recurrent) + 256 (input) k-rows, transposed
#define ALPHA_ 0.001f

#define NGROUP 8           // batch groups (one per XCD under round-robin)
#define GB 16              // samples per group
#define NSLICE 32          // u-slices per group
#define SU 16              // u per slice
#define NWG (NGROUP*NSLICE) // 256  (1 WG/CU, fully resident)
#define NTH 256
#define BU (B_*U_)

typedef __attribute__((ext_vector_type(8))) short bf16x8;
typedef __attribute__((ext_vector_type(4))) float f32x4;
typedef __attribute__((ext_vector_type(4))) int i32x4;
typedef __attribute__((ext_vector_type(2))) int i32x2;
typedef __attribute__((ext_vector_type(4))) unsigned short us4;

// workspace layout (bytes)
#define OFF_WT 0                        // transposed bf16 weights: 3 MiB
#define OFF_H32 (G4_*KT_*2)             // 2 tagged h buffers: 2*BU*4 = 512 KiB
#define OFF_CNT (OFF_H32 + 2*BU*4)      // 8 group counters, 256B apart
#define CNT_DW (NGROUP*64)

__device__ __forceinline__ unsigned short f2b(float f) {
  unsigned u = __builtin_bit_cast(unsigned, f);
  u += 0x7fffu + ((u >> 16) & 1u);   // round-to-nearest-even bf16
  return (unsigned short)(u >> 16);
}

__device__ __forceinline__ float ftanh(float v) {
  v = fminf(fmaxf(v, -15.f), 15.f);
  float e = __expf(2.f * v);
  return (e - 1.f) * __builtin_amdgcn_rcpf(e + 1.f);
}

__global__ void prep_kernel(const float* __restrict__ kern,
                            const float* __restrict__ rker,
                            const float* __restrict__ h0,
                            unsigned short* __restrict__ wt,
                            unsigned* __restrict__ h32,
                            unsigned* __restrict__ cnt) {
  int idx = blockIdx.x * blockDim.x + threadIdx.x;
  int stride = gridDim.x * blockDim.x;
  for (int i = idx; i < G4_ * KT_; i += stride) {
    int col = i / KT_, k = i - col * KT_;
    float v = (k < U_) ? rker[(size_t)k * G4_ + col]
                       : kern[(size_t)(k - U_) * G4_ + col];
    wt[i] = f2b(v);
  }
  for (int i = idx; i < BU; i += stride) {
    h32[i] = ((unsigned)f2b(h0[i]) << 16);   // tag 0 = state entering step 0
    h32[BU + i] = 0xFFFFu;                   // impossible tag (kills stale runs)
  }
  for (int i = idx; i < CNT_DW; i += stride) cnt[i] = 0u;
}

// coalesced bulk h load: per instruction, 64 lanes x 16B = 1KB contiguous
#define LOAD8()                                                        \
  asm volatile(                                                        \
      "global_load_dwordx4 %0, %8, off sc0 sc1\n\t"                    \
      "global_load_dwordx4 %1, %8, off offset:1024 sc0 sc1\n\t"        \
      "global_load_dwordx4 %2, %8, off offset:2048 sc0 sc1\n\t"        \
      "global_load_dwordx4 %3, %8, off offset:3072 sc0 sc1\n\t"        \
      "global_load_dwordx4 %4, %9, off sc0 sc1\n\t"                    \
      "global_load_dwordx4 %5, %9, off offset:1024 sc0 sc1\n\t"        \
      "global_load_dwordx4 %6, %9, off offset:2048 sc0 sc1\n\t"        \
      "global_load_dwordx4 %7, %9, off offset:3072 sc0 sc1"            \
      : "=&v"(v0), "=&v"(v1), "=&v"(v2), "=&v"(v3),                    \
        "=&v"(v4), "=&v"(v5), "=&v"(v6), "=&v"(v7)                     \
      : "v"(ppoll), "v"(ppoll2));                                      \
  __builtin_amdgcn_sched_barrier(0)

#define FENCE8()                                                       \
  asm volatile("s_waitcnt vmcnt(0)"                                    \
      : "+v"(v0), "+v"(v1), "+v"(v2), "+v"(v3),                        \
        "+v"(v4), "+v"(v5), "+v"(v6), "+v"(v7));                       \
  __builtin_amdgcn_sched_barrier(0)

#define CKV(vv) ((((unsigned)(vv)[0] ^ tgv) & 0xffffu) |               \
                 (((unsigned)(vv)[1] ^ tgv) & 0xffffu) |               \
                 (((unsigned)(vv)[2] ^ tgv) & 0xffffu) |               \
                 (((unsigned)(vv)[3] ^ tgv) & 0xffffu))

#define PK(lo, hi) (int)(((unsigned)(hi) & 0xffff0000u) | ((unsigned)(lo) >> 16))

// strip tags from one 16B chunk -> 8B bf16 pair-write to swizzled LDS
// thread (wave, lane) chunk j covers h[row = wave*4 + (j>>1)][u = (j&1)*256 + lane*4 .. +3]
#define PACK2(vv, k)                                                         \
  { const int r_ = 4 * wv + ((k) >> 1);                                      \
    const int ba_ = (r_ * 1024 + (((k) & 1) << 9) + 8 * ln) ^ ((r_ & 7) << 4); \
    i32x2 d_ = { PK((vv)[0], (vv)[1]), PK((vv)[2], (vv)[3]) };               \
    *(i32x2*)(hdst + ba_) = d_; }

__global__ __launch_bounds__(NTH, 1) void plstm_kernel(
    const float* __restrict__ x, const float* __restrict__ h0,
    const float* __restrict__ c0, const float* __restrict__ t0,
    const float* __restrict__ bias, const float* __restrict__ tg,
    const unsigned short* __restrict__ wt,
    unsigned* h32, unsigned* cnt, float* __restrict__ out) {
  const int wg = blockIdx.x;
  const int g = wg & 7, sl = wg >> 3;   // group == XCD (round-robin locality)
  const int b0 = g * GB, u0 = sl * SU;
  const int tid = threadIdx.x;
  const int wave = tid >> 6, lane = tid & 63;

  __shared__ unsigned short h_lds[2][GB * U_];   // 2 x 16 KiB, XOR-swizzled
  __shared__ unsigned short x_lds[2][GB * D_];   // 2 x 8 KiB
  __shared__ float z_lds[2][GB][68];             // 64 + pad
  __shared__ unsigned wgarr[4];                  // per-WG arrive slots

  // ---- weight fragments (transposed layout: contiguous 16B per frag) ----
  bf16x8 br[16], bx[8];
  {
    const int kr0 = (lane >> 4) * 8;
    const int col0 = wave * U_ + u0 + (lane & 15);
    const unsigned short* w0 = wt + (size_t)col0 * KT_;
#pragma unroll
    for (int kt = 0; kt < 16; ++kt) br[kt] = *(const bf16x8*)(w0 + kt * 32 + kr0);
#pragma unroll
    for (int kt = 0; kt < 8; ++kt)  bx[kt] = *(const bf16x8*)(w0 + U_ + kt * 32 + kr0);
  }
  const float bias_l = bias[wave * U_ + u0 + (lane & 15)];

  // ---- per-thread elementwise state: (sample srow, single u) ----
  const int srow = tid >> 4;
  const int j = tid & 15;
  const int bb = b0 + srow;
  const int uu = u0 + j;
  float c_st = c0[bb * U_ + uu];
  float h_st = h0[bb * U_ + uu];
  const float t_0 = t0[bb * U_ + uu];
  const float per = tg[uu];
  const float shf = tg[U_ + uu];
  const float ron = tg[2 * U_ + uu];

  const int arow = lane & 15;
  const int koff = (lane >> 4) * 16;
  const int swzA = (arow & 7) << 4;
  const int swzR = (srow & 7) << 4;
  const int wv = wave, ln = lane;

  auto stage_x = [&](int t, int buf) {
    const int f0 = j * 16;
    const float* xp = x + ((size_t)bb * T_ + t) * D_ + f0;
    char* base = (char*)&x_lds[buf][0];
#pragma unroll
    for (int q = 0; q < 4; ++q) {
      float4 v = *(const float4*)(xp + q * 4);
      us4 pk = { f2b(v.x), f2b(v.y), f2b(v.z), f2b(v.w) };
      *(us4*)(base + ((srow * 512 + (f0 + q * 4) * 2) ^ swzR)) = pk;
    }
  };

  stage_x(0, 0);
  stage_x(1, 1);
  if (tid < 4) wgarr[tid] = 0u;

  // wave-linear bulk pointers: wave w covers group-slab bytes [w*8K,(w+1)*8K)
  const unsigned* gslab0 = h32 + (size_t)b0 * U_;
  const int poff = wave * 2048 + lane * 4;   // dwords
  unsigned* cnt_g = cnt + g * 64;

  // prologue speculative load for step 0 (prep data, tags==0, always fresh)
  i32x4 v0, v1, v2, v3, v4, v5, v6, v7;
  {
    const unsigned* ppoll = gslab0 + poff;
    const unsigned* ppoll2 = ppoll + 1024;
    LOAD8();
  }
  __syncthreads();   // covers x staging + wgarr init

  for (int step = 0; step < T_; ++step) {
    const int par = step & 1;

    // ---- (0) time-gate coefficient (hidden under spec-load latency) ----
    float kk;
    {
      float xx = t_0 + (float)(step + 1) - shf;
      float ph = (xx - per * floorf(xx / per)) / per;
      kk = (ph <= 0.5f * ron) ? (2.f * ph / ron)
         : ((ph <= ron) ? (2.f - 2.f * ph / ron) : (ALPHA_ * ph));
    }

    // ---- (1) x-partial GEMM in the spec-load shadow ----
    f32x4 aa = { bias_l, bias_l, bias_l, bias_l };
    f32x4 ab = { 0.f, 0.f, 0.f, 0.f };
    {
      const char* xb = (const char*)&x_lds[par][0];
#pragma unroll
      for (int kt = 0; kt < 8; ++kt) {
        bf16x8 a = *(const bf16x8*)(xb + ((arow * 512 + kt * 64 + koff) ^ swzA));
        if (kt & 1) ab = __builtin_amdgcn_mfma_f32_16x16x32_bf16(a, bx[kt], ab, 0, 0, 0);
        else        aa = __builtin_amdgcn_mfma_f32_16x16x32_bf16(a, bx[kt], aa, 0, 0, 0);
      }
    }

    // ---- (2) validate speculative data; slow path = counter wait + reload ----
    const unsigned tgv = (unsigned)step;
    FENCE8();
    {
      unsigned bad = CKV(v0) | CKV(v1) | CKV(v2) | CKV(v3) |
                     CKV(v4) | CKV(v5) | CKV(v6) | CKV(v7);
      if (bad) {
        // cheap one-line wait: counter == 32*step iff all WGs arrived for step
        const unsigned tgt = 32u * (unsigned)step;
        while (__hip_atomic_load(cnt_g, __ATOMIC_RELAXED,
                                 __HIP_MEMORY_SCOPE_AGENT) < tgt)
          __builtin_amdgcn_s_sleep(2);
        const unsigned* ppoll = gslab0 + (size_t)par * BU + poff;
        const unsigned* ppoll2 = ppoll + 1024;
        for (;;) {   // counter semantics guarantee first pass; loop = safety net
          LOAD8();
          FENCE8();
          bad = CKV(v0) | CKV(v1) | CKV(v2) | CKV(v3) |
                CKV(v4) | CKV(v5) | CKV(v6) | CKV(v7);
          if (!bad) break;
          __builtin_amdgcn_s_sleep(1);
        }
      }
    }

    // ---- (3) strip tags -> swizzled h_lds[par] ----
    // WAR on h_lds[par] (vs GEMM read at step-2) is covered: passing the tag
    // check for step s implies all waves finished gates(s-1) ⊇ h-GEMM(s-2).
    {
      char* hdst = (char*)&h_lds[par][0];
      PACK2(v0, 0); PACK2(v1, 1); PACK2(v2, 2); PACK2(v3, 3);
      PACK2(v4, 4); PACK2(v5, 5); PACK2(v6, 6); PACK2(v7, 7);
    }
    __syncthreads();   // S1: h_lds[par] ready

    // ---- (4) recurrent GEMM (2 interleaved acc chains) ----
    {
      const char* hbm = (const char*)&h_lds[par][0];
#pragma unroll
      for (int kt = 0; kt < 16; ++kt) {
        bf16x8 a = *(const bf16x8*)(hbm + ((arow * 1024 + kt * 64 + koff) ^ swzA));
        if (kt & 1) ab = __builtin_amdgcn_mfma_f32_16x16x32_bf16(a, br[kt], ab, 0, 0, 0);
        else        aa = __builtin_amdgcn_mfma_f32_16x16x32_bf16(a, br[kt], aa, 0, 0, 0);
      }
    }
    const f32x4 acc = aa + ab;

    // ---- (5) z exchange (C/D: col=lane&15, row=(lane>>4)*4+r) ----
#pragma unroll
    for (int r2 = 0; r2 < 4; ++r2)
      z_lds[par][(lane >> 4) * 4 + r2][wave * 16 + (lane & 15)] = acc[r2];
    __syncthreads();   // S2: z ready

    // ---- (6) gates (single u/thread): h first -> tagged store ASAP ----
    float chat;
    {
      const float* zr = &z_lds[par][srow][0];
      const float zi = zr[j], zf = zr[16 + j], zc = zr[32 + j], zo = zr[48 + j];
      float ig = fminf(fmaxf(0.2f * zi + 0.5f, 0.f), 1.f);
      float fg = fminf(fmaxf(0.2f * zf + 0.5f, 0.f), 1.f);
      float og = fminf(fmaxf(0.2f * zo + 0.5f, 0.f), 1.f);
      chat = fg * c_st + ig * ftanh(zc);
      float hhat = og * ftanh(chat);
      h_st = kk * hhat + (1.f - kk) * h_st;
      unsigned hv = ((unsigned)f2b(h_st) << 16) | (unsigned)(step + 1);
      const unsigned* hp = h32 + (size_t)((step + 1) & 1) * BU + bb * U_ + uu;
      asm volatile("global_store_dword %0, %1, off sc0 sc1"
                   :: "v"(hp), "v"(hv) : "memory");
    }

    // ---- (7) drain own store, barrier-free hierarchical arrive ----
    asm volatile("s_waitcnt vmcnt(0)" ::: "memory");
    if (lane == 0) {
      unsigned old = atomicAdd(&wgarr[step & 3], 1u);  // LDS, per-wave arrive
      if (old == 3u) {                                  // 4th wave of this WG
        wgarr[step & 3] = 0u;
        atomicAdd(cnt_g, 1u);                           // agent scope (proven)
      }
    }

    // ---- (8) speculative bulk load for next step (fire immediately) ----
    if (step + 1 < T_) {
      const unsigned* ppoll = gslab0 + (size_t)((step + 1) & 1) * BU + poff;
      const unsigned* ppoll2 = ppoll + 1024;
      LOAD8();
    }

    // ---- (9) off-critical-path tail ----
    c_st = kk * chat + (1.f - kk) * c_st;
    out[((size_t)bb * T_ + step) * U_ + uu] = h_st;
    if (step + 2 < T_) stage_x(step + 2, par);
  }
}

extern "C" void kernel_launch(void* const* d_in, const int* in_sizes, int n_in,
                              void* d_out, int out_size, void* d_ws,
                              size_t ws_size, hipStream_t stream) {
  const float* x    = (const float*)d_in[0];
  const float* h0   = (const float*)d_in[1];
  const float* c0   = (const float*)d_in[2];
  const float* t0   = (const float*)d_in[3];
  const float* kern = (const float*)d_in[4];
  const float* rker = (const float*)d_in[5];
  const float* bias = (const float*)d_in[6];
  const float* tg   = (const float*)d_in[7];
  float* out = (float*)d_out;

  char* ws = (char*)d_ws;
  unsigned short* wt = (unsigned short*)(ws + OFF_WT);
  unsigned* h32      = (unsigned*)(ws + OFF_H32);
  unsigned* cnt      = (unsigned*)(ws + OFF_CNT);

  prep_kernel<<<1024, 256, 0, stream>>>(kern, rker, h0, wt, h32, cnt);
  plstm_kernel<<<NWG, NTH, 0, stream>>>(x, h0, c0, t0, bias, tg, wt, h32,
                                        cnt, out);
}

// Round 8
// 5210.184 us; speedup vs baseline: 1.9651x; 1.9651x over previous
//
#include <hip/hip_runtime.h>
#include <hip/hip_bf16.h>
#include <math.h>

#define B_ 128
#define T_ 2048
#define D_ 256
#define U_ 512
#define G4_ 2048
#define KT_ 768            // 512 (recurrent) + 256 (input) k-rows, transposed
#define ALPHA_ 0.001f

#define NGROUP 8           // batch groups (one per XCD under round-robin)
#define GB 16              // samples per group
#define NSLICE 32          // u-slices per group
#define SU 16              // u per slice
#define NWG (NGROUP*NSLICE) // 256  (1 WG/CU, fully resident)
#define NTH 256
#define BU (B_*U_)

typedef __attribute__((ext_vector_type(8))) short bf16x8;
typedef __attribute__((ext_vector_type(4))) float f32x4;
typedef __attribute__((ext_vector_type(4))) int i32x4;
typedef __attribute__((ext_vector_type(2))) int i32x2;
typedef __attribute__((ext_vector_type(4))) unsigned short us4;

// workspace layout (bytes)
#define OFF_WT 0                        // transposed bf16 weights: 3 MiB
#define OFF_H32 (G4_*KT_*2)             // 2 tagged h buffers: 2*BU*4 = 512 KiB
#define OFF_CNT (OFF_H32 + 2*BU*4)      // 8 group counters, 256B apart
#define CNT_DW (NGROUP*64)

__device__ __forceinline__ unsigned short f2b(float f) {
  unsigned u = __builtin_bit_cast(unsigned, f);
  u += 0x7fffu + ((u >> 16) & 1u);   // round-to-nearest-even bf16
  return (unsigned short)(u >> 16);
}

__device__ __forceinline__ float ftanh(float v) {
  v = fminf(fmaxf(v, -15.f), 15.f);
  float e = __expf(2.f * v);
  return (e - 1.f) * __builtin_amdgcn_rcpf(e + 1.f);
}

__global__ void prep_kernel(const float* __restrict__ kern,
                            const float* __restrict__ rker,
                            const float* __restrict__ h0,
                            unsigned short* __restrict__ wt,
                            unsigned* __restrict__ h32,
                            unsigned* __restrict__ cnt) {
  int idx = blockIdx.x * blockDim.x + threadIdx.x;
  int stride = gridDim.x * blockDim.x;
  for (int i = idx; i < G4_ * KT_; i += stride) {
    int col = i / KT_, k = i - col * KT_;
    float v = (k < U_) ? rker[(size_t)k * G4_ + col]
                       : kern[(size_t)(k - U_) * G4_ + col];
    wt[i] = f2b(v);
  }
  for (int i = idx; i < BU; i += stride) {
    h32[i] = ((unsigned)f2b(h0[i]) << 16);   // tag 0 = state entering step 0
    h32[BU + i] = 0xFFFFu;                   // impossible tag (kills stale runs)
  }
  for (int i = idx; i < CNT_DW; i += stride) cnt[i] = 0u;
}

// coalesced bulk h load: per instruction, 64 lanes x 16B = 1KB contiguous
#define LOAD8()                                                        \
  asm volatile(                                                        \
      "global_load_dwordx4 %0, %8, off sc0 sc1\n\t"                    \
      "global_load_dwordx4 %1, %8, off offset:1024 sc0 sc1\n\t"        \
      "global_load_dwordx4 %2, %8, off offset:2048 sc0 sc1\n\t"        \
      "global_load_dwordx4 %3, %8, off offset:3072 sc0 sc1\n\t"        \
      "global_load_dwordx4 %4, %9, off sc0 sc1\n\t"                    \
      "global_load_dwordx4 %5, %9, off offset:1024 sc0 sc1\n\t"        \
      "global_load_dwordx4 %6, %9, off offset:2048 sc0 sc1\n\t"        \
      "global_load_dwordx4 %7, %9, off offset:3072 sc0 sc1"            \
      : "=&v"(v0), "=&v"(v1), "=&v"(v2), "=&v"(v3),                    \
        "=&v"(v4), "=&v"(v5), "=&v"(v6), "=&v"(v7)                     \
      : "v"(ppoll), "v"(ppoll2));                                      \
  __builtin_amdgcn_sched_barrier(0)

#define FENCE8()                                                       \
  asm volatile("s_waitcnt vmcnt(0)"                                    \
      : "+v"(v0), "+v"(v1), "+v"(v2), "+v"(v3),                        \
        "+v"(v4), "+v"(v5), "+v"(v6), "+v"(v7));                       \
  __builtin_amdgcn_sched_barrier(0)

#define CKV(vv) ((((unsigned)(vv)[0] ^ tgv) & 0xffffu) |               \
                 (((unsigned)(vv)[1] ^ tgv) & 0xffffu) |               \
                 (((unsigned)(vv)[2] ^ tgv) & 0xffffu) |               \
                 (((unsigned)(vv)[3] ^ tgv) & 0xffffu))

#define PK(lo, hi) (int)(((unsigned)(hi) & 0xffff0000u) | ((unsigned)(lo) >> 16))

// strip tags from one 16B chunk -> 8B bf16 pair-write to swizzled LDS
// chunk k covers h[row = wave*4 + (k>>1)][u = (k&1)*256 + lane*4 .. +3]
#define PACK2(vv, k)                                                         \
  { const int r_ = 4 * wv + ((k) >> 1);                                      \
    const int ba_ = (r_ * 1024 + (((k) & 1) << 9) + 8 * ln) ^ ((r_ & 7) << 4); \
    i32x2 d_ = { PK((vv)[0], (vv)[1]), PK((vv)[2], (vv)[3]) };               \
    *(i32x2*)(hdst + ba_) = d_; }

__global__ __launch_bounds__(NTH, 1) void plstm_kernel(
    const float* __restrict__ x, const float* __restrict__ h0,
    const float* __restrict__ c0, const float* __restrict__ t0,
    const float* __restrict__ bias, const float* __restrict__ tg,
    const unsigned short* __restrict__ wt,
    unsigned* h32, unsigned* cnt, float* __restrict__ out) {
  const int wg = blockIdx.x;
  const int g = wg & 7, sl = wg >> 3;   // group == XCD (round-robin locality)
  const int b0 = g * GB, u0 = sl * SU;
  const int tid = threadIdx.x;
  const int wave = tid >> 6, lane = tid & 63;

  __shared__ unsigned short h_lds[2][GB * U_];   // 2 x 16 KiB, XOR-swizzled
  __shared__ unsigned short x_lds[2][GB * D_];   // 2 x 8 KiB
  __shared__ float z_lds[2][GB][68];             // 64 + pad
  __shared__ unsigned wgarr[4];                  // per-WG arrive slots

  // ---- weight fragments (transposed layout: contiguous 16B per frag) ----
  bf16x8 br[16], bx[8];
  {
    const int kr0 = (lane >> 4) * 8;
    const int col0 = wave * U_ + u0 + (lane & 15);
    const unsigned short* w0 = wt + (size_t)col0 * KT_;
#pragma unroll
    for (int kt = 0; kt < 16; ++kt) br[kt] = *(const bf16x8*)(w0 + kt * 32 + kr0);
#pragma unroll
    for (int kt = 0; kt < 8; ++kt)  bx[kt] = *(const bf16x8*)(w0 + U_ + kt * 32 + kr0);
  }
  const float bias_l = bias[wave * U_ + u0 + (lane & 15)];

  // ---- per-thread elementwise state: (sample srow, single u) ----
  const int srow = tid >> 4;
  const int j = tid & 15;
  const int bb = b0 + srow;
  const int uu = u0 + j;
  float c_st = c0[bb * U_ + uu];
  float h_st = h0[bb * U_ + uu];
  const float t_0 = t0[bb * U_ + uu];
  const float per = tg[uu];
  const float shf = tg[U_ + uu];
  const float ron = tg[2 * U_ + uu];

  const int arow = lane & 15;
  const int koff = (lane >> 4) * 16;
  const int swzA = (arow & 7) << 4;
  const int swzR = (srow & 7) << 4;
  const int wv = wave, ln = lane;

  auto stage_x = [&](int t, int buf) {
    const int f0 = j * 16;
    const float* xp = x + ((size_t)bb * T_ + t) * D_ + f0;
    char* base = (char*)&x_lds[buf][0];
#pragma unroll
    for (int q = 0; q < 4; ++q) {
      float4 v = *(const float4*)(xp + q * 4);
      us4 pk = { f2b(v.x), f2b(v.y), f2b(v.z), f2b(v.w) };
      *(us4*)(base + ((srow * 512 + (f0 + q * 4) * 2) ^ swzR)) = pk;
    }
  };

  stage_x(0, 0);
  stage_x(1, 1);
  if (tid < 4) wgarr[tid] = 0u;
  __syncthreads();   // covers prologue x staging + wgarr init

  // wave-linear bulk pointers: wave w covers group-slab bytes [w*8K,(w+1)*8K)
  const unsigned* gslab0 = h32 + (size_t)b0 * U_;
  const int poff = wave * 2048 + lane * 4;   // dwords
  unsigned* cnt_g = cnt + g * 64;

  for (int step = 0; step < T_; ++step) {
    const int par = step & 1;

    // ---- (1) per-wave counter wait (uniform addr -> 1 txn per poll) ----
    // counter >= 32*step  <=>  all 32 WGs arrived for step-1 (h(step) stored)
    if (step > 0) {
      const unsigned tgt = 32u * (unsigned)step;
      while (__hip_atomic_load(cnt_g, __ATOMIC_RELAXED,
                               __HIP_MEMORY_SCOPE_AGENT) < tgt)
        __builtin_amdgcn_s_sleep(1);
    }

    // ---- (2) single fresh bulk h load, fired immediately on poll pass ----
    const unsigned* ppoll = gslab0 + (size_t)par * BU + poff;
    const unsigned* ppoll2 = ppoll + 1024;
    i32x4 v0, v1, v2, v3, v4, v5, v6, v7;
    LOAD8();

    // ---- (3) time-gate coeff + x-partial GEMM in the load RTT shadow ----
    float kk;
    {
      float xx = t_0 + (float)(step + 1) - shf;
      float ph = (xx - per * floorf(xx / per)) / per;
      kk = (ph <= 0.5f * ron) ? (2.f * ph / ron)
         : ((ph <= ron) ? (2.f - 2.f * ph / ron) : (ALPHA_ * ph));
    }
    f32x4 aa = { bias_l, bias_l, bias_l, bias_l };
    f32x4 ab = { 0.f, 0.f, 0.f, 0.f };
    {
      // x_lds[par] written at tail(step-2); separated by S1/S2(step-1) ✓
      const char* xb = (const char*)&x_lds[par][0];
#pragma unroll
      for (int kt = 0; kt < 8; ++kt) {
        bf16x8 a = *(const bf16x8*)(xb + ((arow * 512 + kt * 64 + koff) ^ swzA));
        if (kt & 1) ab = __builtin_amdgcn_mfma_f32_16x16x32_bf16(a, bx[kt], ab, 0, 0, 0);
        else        aa = __builtin_amdgcn_mfma_f32_16x16x32_bf16(a, bx[kt], aa, 0, 0, 0);
      }
    }

    // ---- (4) validate tags; stale (rare, no-drain straggler) -> reload ----
    const unsigned tgv = (unsigned)step;
    FENCE8();
    for (;;) {
      unsigned bad = CKV(v0) | CKV(v1) | CKV(v2) | CKV(v3) |
                     CKV(v4) | CKV(v5) | CKV(v6) | CKV(v7);
      if (!bad) break;
      __builtin_amdgcn_s_sleep(1);
      LOAD8();
      FENCE8();
    }

    // ---- (5) strip tags -> swizzled h_lds[par] ----
    // WAR vs h-GEMM read(step-2, same parity): separated by S1/S2(step-1) ✓
    {
      char* hdst = (char*)&h_lds[par][0];
      PACK2(v0, 0); PACK2(v1, 1); PACK2(v2, 2); PACK2(v3, 3);
      PACK2(v4, 4); PACK2(v5, 5); PACK2(v6, 6); PACK2(v7, 7);
    }
    __syncthreads();   // S1: h_lds[par] ready

    // ---- (6) recurrent GEMM (2 interleaved acc chains) ----
    {
      const char* hbm = (const char*)&h_lds[par][0];
#pragma unroll
      for (int kt = 0; kt < 16; ++kt) {
        bf16x8 a = *(const bf16x8*)(hbm + ((arow * 1024 + kt * 64 + koff) ^ swzA));
        if (kt & 1) ab = __builtin_amdgcn_mfma_f32_16x16x32_bf16(a, br[kt], ab, 0, 0, 0);
        else        aa = __builtin_amdgcn_mfma_f32_16x16x32_bf16(a, br[kt], aa, 0, 0, 0);
      }
    }
    const f32x4 acc = aa + ab;

    // ---- (7) z exchange (C/D: col=lane&15, row=(lane>>4)*4+r) ----
#pragma unroll
    for (int r2 = 0; r2 < 4; ++r2)
      z_lds[par][(lane >> 4) * 4 + r2][wave * 16 + (lane & 15)] = acc[r2];
    __syncthreads();   // S2: z ready

    // ---- (8) gates: h path first -> tagged store ASAP, arrive, then tail ----
    float chat;
    {
      const float* zr = &z_lds[par][srow][0];
      const float zi = zr[j], zf = zr[16 + j], zc = zr[32 + j], zo = zr[48 + j];
      float ig = fminf(fmaxf(0.2f * zi + 0.5f, 0.f), 1.f);
      float fg = fminf(fmaxf(0.2f * zf + 0.5f, 0.f), 1.f);
      float og = fminf(fmaxf(0.2f * zo + 0.5f, 0.f), 1.f);
      chat = fg * c_st + ig * ftanh(zc);
      float hhat = og * ftanh(chat);
      h_st = kk * hhat + (1.f - kk) * h_st;
      unsigned hv = ((unsigned)f2b(h_st) << 16) | (unsigned)(step + 1);
      const unsigned* hp = h32 + (size_t)((step + 1) & 1) * BU + bb * U_ + uu;
      asm volatile("global_store_dword %0, %1, off sc0 sc1"
                   :: "v"(hp), "v"(hv) : "memory");
    }

    // ---- (9) barrier-free hierarchical arrive — NO drain (tags cover) ----
    // per-wave: all 64 lanes' h-stores issued before lane0's LDS add
    // (program order); tag validation absorbs store-vs-add visibility races.
    if (lane == 0) {
      unsigned old = atomicAdd(&wgarr[step & 3], 1u);  // LDS, per-wave arrive
      if (old == 3u) {                                  // 4th wave of this WG
        wgarr[step & 3] = 0u;
        atomicAdd(cnt_g, 1u);                           // agent scope (proven)
      }
    }

    // ---- (10) off-critical-path tail ----
    c_st = kk * chat + (1.f - kk) * c_st;
    out[((size_t)bb * T_ + step) * U_ + uu] = h_st;
    if (step + 2 < T_) stage_x(step + 2, par);   // write x_lds[par] for t+2
  }
}

extern "C" void kernel_launch(void* const* d_in, const int* in_sizes, int n_in,
                              void* d_out, int out_size, void* d_ws,
                              size_t ws_size, hipStream_t stream) {
  const float* x    = (const float*)d_in[0];
  const float* h0   = (const float*)d_in[1];
  const float* c0   = (const float*)d_in[2];
  const float* t0   = (const float*)d_in[3];
  const float* kern = (const float*)d_in[4];
  const float* rker = (const float*)d_in[5];
  const float* bias = (const float*)d_in[6];
  const float* tg   = (const float*)d_in[7];
  float* out = (float*)d_out;

  char* ws = (char*)d_ws;
  unsigned short* wt = (unsigned short*)(ws + OFF_WT);
  unsigned* h32      = (unsigned*)(ws + OFF_H32);
  unsigned* cnt      = (unsigned*)(ws + OFF_CNT);

  prep_kernel<<<1024, 256, 0, stream>>>(kern, rker, h0, wt, h32, cnt);
  plstm_kernel<<<NWG, NTH, 0, stream>>>(x, h0, c0, t0, bias, tg, wt, h32,
                                        cnt, out);
}